// Round 2
// baseline (505.203 us; speedup 1.0000x reference)
//
#include <hip/hip_runtime.h>

// Floyd-Steinberg dithering, BIT_WIDTH=1. 96 images of 512x512 fp32.
// Round 9: single fused kernel (pack + dither + unpack), producer-consumer
// over device-scope flags.
//   blocks 0..767  : pack band (w = bid/96, img = bid%96)  [band-major so all
//                    band-0 blocks dispatch first]. LDS ring transpose ->
//                    coalesced 512B pair stores -> release flag.
//   blocks 768..863: dither one image. Each wave acquires its band's flag,
//                    then runs the R8 wavefront recurrence (modulo-renamed
//                    pipeline, med3 clamp, -8 sentinel). Bits go to LDS;
//                    after its 40 chunks each wave unpacks its own 64 rows
//                    as coalesced float4 stores. No unpack kernel, no global
//                    yb, no inter-kernel stream gaps.
// Deadlock-free by construction: pack blocks never wait; only 96 dither
// blocks exist (< 256 CUs), so pack always has >=160 CUs to run on,
// regardless of dispatch order.
// Handoff ordering: producer __syncthreads (drains vmcnt) + __threadfence +
// AGENT-scope release store; consumer AGENT-scope acquire load spin.
// Bit-exactness (R1-R8): ref op order, rintf (round-half-even), contract OFF,
// med3(v,0,1)==min(max(v,0),1) for non-NaN, sentinel path err==0 exactly.

#define F_UL 0.0625f   // 1/16
#define F_U  0.3125f   // 5/16
#define F_UR 0.1875f   // 3/16
#define F_L  0.4375f   // 7/16

typedef unsigned long long ull;

constexpr int WW    = 512;
constexpr int IMG   = WW * WW;
constexpr int NIMG  = 96;
constexpr int NW    = 8;      // waves per dither block / bands per image
constexpr int BUFW  = 792;    // boundary region floats (+128 base offset)
constexpr int NCH   = 40;     // 16-step chunks (640 steps per wave)
constexpr int LAG   = 10;     // producer lead in chunks
constexpr int PPAIR = 320;    // step-pairs per (img,band) region
constexpr int NPACK = NIMG * NW;          // 768 pack blocks
constexpr int GRID  = NPACK + NIMG;       // + 96 dither blocks

constexpr size_t XP_FLOATS = (size_t)NIMG * NW * PPAIR * 128;
constexpr size_t XP_BYTES  = XP_FLOATS * 4;        // 125,829,120 B
constexpr size_t XP_SLACK  = 8192;                 // prefetch overrun (16 pairs)
constexpr size_t XP_OFF    = 4u * 1024 * 1024;     // xp after flag region
constexpr size_t WS_NEED   = XP_OFF + XP_BYTES + XP_SLACK;
constexpr size_t FLAGS_BYTES = (size_t)NPACK * 4;  // 3072 B at ws offset 0

// shared-memory overlay (both block types declare the same block)
constexpr int BND_BYTES  = (NW + 1) * BUFW * 4;    // 28,512
constexpr int FLAGS_OFF  = BND_BYTES;              // 28,512 (+32)
constexpr int BITS_OFF   = BND_BYTES + 32;         // 28,544
constexpr int BITS_BYTES = NW * 11 * 64 * 8;       // 45,056 (win 10 = pad)
constexpr int SMEM_BYTES = BITS_OFF + BITS_BYTES;  // 73,600 (pack needs 66,560)

__device__ __forceinline__ float wave_shr1(float v, float fill) {
  int r = __builtin_amdgcn_update_dpp(__float_as_int(fill), __float_as_int(v),
                                      0x138 /*wave_shr:1*/, 0xF, 0xF, false);
  return __int_as_float(r);
}

__device__ __forceinline__ float pp(float xv) {   // x -> x01, ref op order
#pragma clang fp contract(off)
  float xc = fminf(fmaxf(xv, -1.0f), 1.0f);
  return (xc + 1.0f) * 0.5f;
}

__global__ __launch_bounds__(512, 1)
void fused(const float* __restrict__ xin, float* __restrict__ xp,
           int* __restrict__ gflags, float* __restrict__ yout) {
  __shared__ alignas(16) unsigned char smem[SMEM_BYTES];
  const int bid = blockIdx.x;
  const int tid = threadIdx.x;

  if (bid < NPACK) {
    // ---------------- pack block: band w of image img ----------------
    const int w   = bid / NIMG;          // band-major: all band-0 first
    const int img = bid % NIMG;
    const int wv  = tid >> 6, l = tid & 63;
    float* ring = (float*)smem;          // 4 slots x 64*65 floats

    const float* xg = xin + (size_t)img * IMG + (size_t)w * 64 * WW;
    float* ob = xp + ((size_t)(img * NW + w) * PPAIR) * 128;

    auto load_tile = [&](int t) {        // tile t = cols 64t..64t+63 -> slot t&3
      float* dst = ring + (t & 3) * 4160;
      const float* src = xg + 64 * t;
#pragma unroll
      for (int k = 0; k < 2; ++k) {
        int flat = tid + 512 * k;        // 1024 quads, 512 threads
        int row = flat >> 4, cq = flat & 15;
        float4 v = *(const float4*)(src + row * WW + cq * 4);
        float* d = dst + row * 65 + cq * 4;
        d[0] = pp(v.x); d[1] = pp(v.y); d[2] = pp(v.z); d[3] = pp(v.w);
      }
    };

    load_tile(0);
    __syncthreads();
    // round t emits pairs 32t..32t+31 (needs tiles t-2..t); slot (t+1)&3 is
    // disjoint from slots (t-2..t)&3.
    for (int t = 0; t < 10; ++t) {
      if (t < 7) load_tile(t + 1);
      const int Mb = 32 * t + 4 * wv;    // 8 waves x 4 pairs = 32 pairs/round
#pragma unroll
      for (int i = 0; i < 4; ++i) {
        const int M  = Mb + i;
        const int g  = 2 * (M - l);            // global column of first element
        const int gm = g & 511;                // safe LDS index for invalid g
        const int idx = ((gm >> 6) & 3) * 4160 + l * 65 + (gm & 63);
        const bool ok = ((unsigned)g < 512u);
        float va = ring[idx], vb = ring[idx + 1];   // bank (2M-l)%32: 2-way, free
        float2 v = make_float2(ok ? va : -8.0f, ok ? vb : -8.0f);
        *(float2*)(ob + (size_t)M * 128 + 2 * l) = v;   // 512B coalesced / wave
      }
      __syncthreads();
    }
    // publish: syncthreads above drained vmcnt for all waves; fence + release.
    __threadfence();
    if (tid == 0)
      __hip_atomic_store(&gflags[img * NW + w], 1, __ATOMIC_RELEASE,
                         __HIP_MEMORY_SCOPE_AGENT);
    return;
  }

  // ---------------- dither block: one image ----------------
  const int  img  = bid - NPACK;
  const int  wave = tid >> 6;
  const int  lane = tid & 63;
  const bool l63  = (lane == 63);

  float* bnd  = (float*)smem;
  int*   flags = (int*)(smem + FLAGS_OFF);
  ull (*bits)[11][64] = (ull (*)[11][64])(smem + BITS_OFF);

  for (int i = tid; i < (NW + 1) * BUFW; i += 512) bnd[i] = 0.0f;
  if (tid < NW) flags[tid] = 0;
  bits[wave][10][lane] = 0ull;           // pad window (t64+1 == 10 reads)
  __syncthreads();

  // wait for this wave's band to be packed (device-scope handoff)
  {
    const int* gf = gflags + img * NW + wave;
    while (__hip_atomic_load(gf, __ATOMIC_ACQUIRE,
                             __HIP_MEMORY_SCOPE_AGENT) == 0)
      __builtin_amdgcn_s_sleep(16);
  }

  const float* xw = xp + ((size_t)(img * NW + wave) * PPAIR) * 128 + lane * 2;
  float* bufR = bnd + wave * BUFW;
  float* bufW = bnd + (wave + 1) * BUFW;

  // x pipeline: 8 slots x 4 float2. iter8 K consumes slot K%8, loads slot
  // (K+4)%8 with pairs for iter8 K+4 -> loads live 4 iter8s, zero copies.
  float2 X0[4], X1[4], X2[4], X3[4], X4[4], X5[4], X6[4], X7[4];
#pragma unroll
  for (int i = 0; i < 4; ++i) {
    X0[i] = *(const float2*)(xw + (size_t)(0  + i) * 128);
    X1[i] = *(const float2*)(xw + (size_t)(4  + i) * 128);
    X2[i] = *(const float2*)(xw + (size_t)(8  + i) * 128);
    X3[i] = *(const float2*)(xw + (size_t)(12 + i) * 128);
  }

  int seen = 0;                          // cached producer flag (monotonic)
  if (wave) {
    while ((seen = __hip_atomic_load(&flags[wave - 1], __ATOMIC_RELAXED,
                                     __HIP_MEMORY_SCOPE_WORKGROUP)) < LAG)
      __builtin_amdgcn_s_sleep(1);
    __asm__ volatile("s_waitcnt lgkmcnt(0)" ::: "memory");
  }

  float err = 0.0f, s2 = 0.0f;
  float s1 = (lane == 0) ? bufR[129] : 0.0f;
  // q pipeline: 2 slots, parity K%2; loaded at iter8 bottom for K+2.
  float2 Q0[4], Q1[4];
#pragma unroll
  for (int i = 0; i < 4; ++i) {
    Q0[i] = *(const float2*)(bufR + 130 + 2 * i);   // for K=0 (steps 0..7)
    Q1[i] = *(const float2*)(bufR + 138 + 2 * i);   // for K=1 (steps 8..15)
  }

  unsigned accLo = 0u, accHi = 0u;

  auto step = [&](float qv, float xv) -> float {
#pragma clang fp contract(off)
    float e_in = wave_shr1(err, qv);          // err[r-1][c+1]
    float t1   = F_UL * s2;
    float t2   = F_U  * s1;
    float t3   = F_UR * e_in;
    float u    = (t1 + t2) + t3;              // ref's left-to-right order
    float a1   = xv + u;                      // xv = x01 (or -8 sentinel)
    float b    = F_L * err;
    float v    = a1 + b;
    float val  = __builtin_amdgcn_fmed3f(v, 0.0f, 1.0f);  // == clamp, 1 op
    float qn   = rintf(val);                  // round-half-even
    err = val - qn;                           // sentinel path: exactly 0
    s2 = s1; s1 = e_in;
    return qn;                                // 0.0f or 1.0f
  };

  auto iter8 = [&](float2 (&XC)[4], float2 (&XL)[4], float2 (&QC)[4],
                   int T, int bsh, unsigned& acc) {
    // x prefetch: pairs T/2+16..19 (consumed 4 iter8s later, slot renamed)
    const float* lp = xw + (size_t)(T / 2 + 16) * 128;
    XL[0] = *(const float2*)(lp + 0 * 128);
    XL[1] = *(const float2*)(lp + 1 * 128);
    XL[2] = *(const float2*)(lp + 2 * 128);
    XL[3] = *(const float2*)(lp + 3 * 128);

    float p0 = step(QC[0].x, XC[0].x); float e0 = err;
    float p1 = step(QC[0].y, XC[0].y); float e1 = err;
    float p2 = step(QC[1].x, XC[1].x); float e2 = err;
    float p3 = step(QC[1].y, XC[1].y); float e3 = err;
    float p4 = step(QC[2].x, XC[2].x); float e4 = err;
    float p5 = step(QC[2].y, XC[2].y); float e5 = err;
    float p6 = step(QC[3].x, XC[3].x); float e6 = err;
    float p7 = step(QC[3].y, XC[3].y); float e7 = err;

    // boundary prefetch for iteration T+16 (same slot, distance 2)
    QC[0] = *(const float2*)(bufR + (T + 146));
    QC[1] = *(const float2*)(bufR + (T + 148));
    QC[2] = *(const float2*)(bufR + (T + 150));
    QC[3] = *(const float2*)(bufR + (T + 152));

    // bit = exponent bit 29 of qn (1.0f -> 1, 0.0f -> 0); off-chain
    acc |= ((__float_as_uint(p0) >> 29) & 1u) << (bsh + 0);
    acc |= ((__float_as_uint(p1) >> 29) & 1u) << (bsh + 1);
    acc |= ((__float_as_uint(p2) >> 29) & 1u) << (bsh + 2);
    acc |= ((__float_as_uint(p3) >> 29) & 1u) << (bsh + 3);
    acc |= ((__float_as_uint(p4) >> 29) & 1u) << (bsh + 4);
    acc |= ((__float_as_uint(p5) >> 29) & 1u) << (bsh + 5);
    acc |= ((__float_as_uint(p6) >> 29) & 1u) << (bsh + 6);
    acc |= ((__float_as_uint(p7) >> 29) & 1u) << (bsh + 7);

    if (l63) {  // boundary row for next wave; base = T-126+129 = T+3
      float* bw = bufW + (T + 3);
      bw[0] = e0; bw[1] = e1; bw[2] = e2; bw[3] = e3;
      bw[4] = e4; bw[5] = e5; bw[6] = e6; bw[7] = e7;
    }
  };

  auto waitflag = [&](int j) {
    if (wave) {
      int need = j + LAG; if (need > NCH) need = NCH;
      if (seen < need) {
        while ((seen = __hip_atomic_load(&flags[wave - 1], __ATOMIC_RELAXED,
                                         __HIP_MEMORY_SCOPE_WORKGROUP)) < need)
          __builtin_amdgcn_s_sleep(1);
        __asm__ volatile("s_waitcnt lgkmcnt(0)" ::: "memory");
      }
    }
  };
  auto pubflag = [&](int v) {
    if (l63) {
      __asm__ volatile("s_waitcnt lgkmcnt(0)" ::: "memory");
      __hip_atomic_store(&flags[wave], v, __ATOMIC_RELAXED,
                         __HIP_MEMORY_SCOPE_WORKGROUP);
    }
  };

  // body = 4 chunks = 8 iter8s = one 64-step bit window
  for (int jj = 0; jj < NCH; jj += 4) {
    const int T0 = 16 * jj;
    waitflag(jj);
    iter8(X0, X4, Q0, T0 + 0,  0,  accLo);
    iter8(X1, X5, Q1, T0 + 8,  8,  accLo);
    pubflag(jj + 1);
    waitflag(jj + 1);
    iter8(X2, X6, Q0, T0 + 16, 16, accLo);
    iter8(X3, X7, Q1, T0 + 24, 24, accLo);
    pubflag(jj + 2);
    waitflag(jj + 2);
    iter8(X4, X0, Q0, T0 + 32, 0,  accHi);
    iter8(X5, X1, Q1, T0 + 40, 8,  accHi);
    pubflag(jj + 3);
    waitflag(jj + 3);
    iter8(X6, X2, Q0, T0 + 48, 16, accHi);
    iter8(X7, X3, Q1, T0 + 56, 24, accHi);
    pubflag(jj + 4);
    *(uint2*)&bits[wave][jj >> 2][lane] = make_uint2(accLo, accHi);
    accLo = 0u; accHi = 0u;
  }

  // ---- unpack tail: this wave's 64 rows, bits (LDS) -> ±1.0f coalesced ----
  float* ybase = yout + (size_t)img * IMG + (size_t)(wave * 64) * WW + 8 * lane;
  for (int r = 0; r < 64; ++r) {
    const int t0 = 8 * lane + 2 * r;          // first bit index
    const int t64 = t0 >> 6, sh = t0 & 63;    // sh even, <= 62
    ull w1 = bits[wave][t64][r];
    ull w2 = bits[wave][t64 + 1][r];          // pad window covers t64==9
    unsigned b = (unsigned)((w1 >> sh) | ((w2 << 1) << (63 - sh)));
    float* orow = ybase + (size_t)r * WW;
    float4 v0, v1;
    v0.x = (b & 1u)   ? 1.0f : -1.0f;
    v0.y = (b & 2u)   ? 1.0f : -1.0f;
    v0.z = (b & 4u)   ? 1.0f : -1.0f;
    v0.w = (b & 8u)   ? 1.0f : -1.0f;
    v1.x = (b & 16u)  ? 1.0f : -1.0f;
    v1.y = (b & 32u)  ? 1.0f : -1.0f;
    v1.z = (b & 64u)  ? 1.0f : -1.0f;
    v1.w = (b & 128u) ? 1.0f : -1.0f;
    *(float4*)(orow)     = v0;
    *(float4*)(orow + 4) = v1;
  }
}

// ---------------- fallback: R4/R6 direct-x kernel (known-good) --------------
__global__ __launch_bounds__(512, 1)
void dither_direct(const float* __restrict__ xin, float* __restrict__ yout) {
  __shared__ float bnd[(NW + 1) * BUFW];
  __shared__ int flags[NW];

  const int  tid  = threadIdx.x;
  const int  wave = tid >> 6;
  const int  lane = tid & 63;
  const int  img  = blockIdx.x;
  const bool l63  = (lane == 63);

  for (int i = tid; i < (NW + 1) * BUFW; i += 512) bnd[i] = 0.0f;
  if (tid < NW) flags[tid] = 0;
  __syncthreads();

  const int r = wave * 64 + lane;
  const float* xrow = xin + (size_t)img * IMG + (size_t)r * WW;
  float*       yrow = yout + (size_t)img * IMG + (size_t)r * WW;
  float* bufR = bnd + wave * BUFW;
  float* bufW = bnd + (wave + 1) * BUFW;
  const int c0 = -2 * lane;

  auto ldx = [&](int c) -> float2 { return *(const float2*)(xrow + (c & 511)); };

  float2 A0 = ldx(c0 + 0),  A1 = ldx(c0 + 2),  A2 = ldx(c0 + 4),  A3 = ldx(c0 + 6);
  float2 pB0 = ldx(c0 + 8),  pB1 = ldx(c0 + 10), pB2 = ldx(c0 + 12), pB3 = ldx(c0 + 14);
  float2 pC0 = ldx(c0 + 16), pC1 = ldx(c0 + 18), pC2 = ldx(c0 + 20), pC3 = ldx(c0 + 22);
  float xq0 = pp(A0.x), xq1 = pp(A0.y), xq2 = pp(A1.x), xq3 = pp(A1.y);
  float xq4 = pp(A2.x), xq5 = pp(A2.y), xq6 = pp(A3.x), xq7 = pp(A3.y);
  float2 pA0 = pB0, pA1 = pB1, pA2 = pB2, pA3 = pB3;
  pB0 = pC0; pB1 = pC1; pB2 = pC2; pB3 = pC3;

  if (wave) {
    while (__hip_atomic_load(&flags[wave - 1], __ATOMIC_RELAXED,
                             __HIP_MEMORY_SCOPE_WORKGROUP) < LAG)
      __builtin_amdgcn_s_sleep(1);
    __asm__ volatile("s_waitcnt lgkmcnt(0)" ::: "memory");
  }

  float err = 0.0f, s2 = 0.0f;
  float s1 = (lane == 0) ? bufR[129] : 0.0f;
  float2 qa = *(const float2*)(bufR + 130);
  float2 qb = *(const float2*)(bufR + 132);
  float2 qc = *(const float2*)(bufR + 134);
  float2 qd = *(const float2*)(bufR + 136);
  float2 fa = *(const float2*)(bufR + 138);
  float2 fb = *(const float2*)(bufR + 140);
  float2 fc = *(const float2*)(bufR + 142);
  float2 fd = *(const float2*)(bufR + 144);

  auto step = [&](int c, float qv, float xv) -> float {
#pragma clang fp contract(off)
    float e_in = wave_shr1(err, qv);
    float t1   = F_UL * s2;
    float t2   = F_U  * s1;
    float t3   = F_UR * e_in;
    float u    = (t1 + t2) + t3;
    float a1   = xv + u;
    float b    = F_L * err;
    float v    = a1 + b;
    float val  = fminf(fmaxf(v, 0.0f), 1.0f);
    float qn   = rintf(val);
    float e    = val - qn;
    float en   = ((unsigned)c < 512u) ? e : 0.0f;
    err = en; s2 = s1; s1 = e_in;
    return __builtin_fmaf(qn, 2.0f, -1.0f);
  };

  auto iter8 = [&](int T) {
    const int cg = c0 + T;
    float2 n0 = ldx(cg + 24), n1 = ldx(cg + 26), n2 = ldx(cg + 28), n3 = ldx(cg + 30);
    float2 h0 = *(const float2*)(bufR + (T + 146));
    float2 h1 = *(const float2*)(bufR + (T + 148));
    float2 h2 = *(const float2*)(bufR + (T + 150));
    float2 h3 = *(const float2*)(bufR + (T + 152));
    float w0 = pp(pA0.x), w1 = pp(pA0.y), w2 = pp(pA1.x), w3 = pp(pA1.y);
    float w4 = pp(pA2.x), w5 = pp(pA2.y), w6 = pp(pA3.x), w7 = pp(pA3.y);

    float y0 = step(cg + 0, qa.x, xq0); float e0 = err;
    float y1 = step(cg + 1, qa.y, xq1); float e1 = err;
    float y2 = step(cg + 2, qb.x, xq2); float e2 = err;
    float y3 = step(cg + 3, qb.y, xq3); float e3 = err;
    float y4 = step(cg + 4, qc.x, xq4); float e4 = err;
    float y5 = step(cg + 5, qc.y, xq5); float e5 = err;
    float y6 = step(cg + 6, qd.x, xq6); float e6 = err;
    float y7 = step(cg + 7, qd.y, xq7); float e7 = err;

    if ((unsigned)(cg + 0) < 511u) *(float2*)(yrow + cg + 0) = make_float2(y0, y1);
    if ((unsigned)(cg + 2) < 511u) *(float2*)(yrow + cg + 2) = make_float2(y2, y3);
    if ((unsigned)(cg + 4) < 511u) *(float2*)(yrow + cg + 4) = make_float2(y4, y5);
    if ((unsigned)(cg + 6) < 511u) *(float2*)(yrow + cg + 6) = make_float2(y6, y7);

    if (l63) {
      float* bw = bufW + (cg + 129);
      bw[0] = e0; bw[1] = e1; bw[2] = e2; bw[3] = e3;
      bw[4] = e4; bw[5] = e5; bw[6] = e6; bw[7] = e7;
    }

    xq0 = w0; xq1 = w1; xq2 = w2; xq3 = w3;
    xq4 = w4; xq5 = w5; xq6 = w6; xq7 = w7;
    pA0 = pB0; pA1 = pB1; pA2 = pB2; pA3 = pB3;
    pB0 = n0;  pB1 = n1;  pB2 = n2;  pB3 = n3;
    qa = fa; qb = fb; qc = fc; qd = fd;
    fa = h0; fb = h1; fc = h2; fd = h3;
  };

  for (int j = 0; j < NCH; ++j) {
    if (wave) {
      int need = j + LAG; if (need > NCH) need = NCH;
      while (__hip_atomic_load(&flags[wave - 1], __ATOMIC_RELAXED,
                               __HIP_MEMORY_SCOPE_WORKGROUP) < need)
        __builtin_amdgcn_s_sleep(1);
      __asm__ volatile("s_waitcnt lgkmcnt(0)" ::: "memory");
    }
    iter8(16 * j);
    iter8(16 * j + 8);
    if (l63) {
      __asm__ volatile("s_waitcnt lgkmcnt(0)" ::: "memory");
      __hip_atomic_store(&flags[wave], j + 1, __ATOMIC_RELAXED,
                         __HIP_MEMORY_SCOPE_WORKGROUP);
    }
  }
}

extern "C" void kernel_launch(void* const* d_in, const int* in_sizes, int n_in,
                              void* d_out, int out_size, void* d_ws, size_t ws_size,
                              hipStream_t stream) {
  const float* x = (const float*)d_in[0];
  float*       y = (float*)d_out;
  if (ws_size >= WS_NEED) {
    int*   gflags = (int*)d_ws;                        // 3 KB flag region
    float* xp     = (float*)((char*)d_ws + XP_OFF);
    hipMemsetAsync(d_ws, 0, FLAGS_BYTES, stream);      // clear handoff flags
    fused<<<dim3(GRID), dim3(512), 0, stream>>>(x, xp, gflags, y);
  } else {
    dither_direct<<<dim3(NIMG), dim3(512), 0, stream>>>(x, y);
  }
}

// Round 3
// 314.096 us; speedup vs baseline: 1.6084x; 1.6084x over previous
//
#include <hip/hip_runtime.h>

// Floyd-Steinberg dithering, BIT_WIDTH=1. 96 images of 512x512 fp32.
// Round 10: ONE kernel, no workspace. The xp pack detour (225 MB round-trip +
// 2 extra launches) is eliminated: the recurrence reads x directly -- each
// lane walks its own row sequentially (64 lines/wave live in L1), prefetched
// 4 iter8s (~3400 cyc) ahead of use, far above the ~900-cyc HBM miss.
// pp() + the -8.0f out-of-range sentinel are applied to the prefetched
// values OFF the critical chain (cndmask on prefetch, not on err).
// Output: bits -> LDS (win stride padded to 65 ulls: kills the 8-way bank
// conflict found in R9 -- t64 stride was 512 B = 0 mod 32 banks), then each
// wave unpacks its own 64 rows as coalesced float4 stores.
// R9 lessons applied: 96 blocks = 1 block/CU (no recurrence stacking),
// no AGENT-scope spins, separate __shared__ declarations (alias info).
// Bit-exactness (R1-R9): ref op order, rintf (round-half-even), contract OFF,
// med3(v,0,1)==min(max(v,0),1) for non-NaN, sentinel path err==0 exactly
// (validated bit-exact in R1/R2 benches: absmax 0.0).

#define F_UL 0.0625f   // 1/16
#define F_U  0.3125f   // 5/16
#define F_UR 0.1875f   // 3/16
#define F_L  0.4375f   // 7/16

typedef unsigned long long ull;

constexpr int WW   = 512;
constexpr int IMG  = WW * WW;
constexpr int NIMG = 96;
constexpr int NW   = 8;      // waves per block / bands per image
constexpr int BUFW = 792;    // boundary region floats (+128 base offset)
constexpr int NCH  = 40;     // 16-step chunks (640 steps per wave)
constexpr int LAG  = 10;     // producer lead in chunks

__device__ __forceinline__ float wave_shr1(float v, float fill) {
  int r = __builtin_amdgcn_update_dpp(__float_as_int(fill), __float_as_int(v),
                                      0x138 /*wave_shr:1*/, 0xF, 0xF, false);
  return __int_as_float(r);
}

__device__ __forceinline__ float pp(float xv) {   // x -> x01, ref op order
#pragma clang fp contract(off)
  float xc = fminf(fmaxf(xv, -1.0f), 1.0f);
  return (xc + 1.0f) * 0.5f;
}

__global__ __launch_bounds__(512, 1)
void dither_fused(const float* __restrict__ xin, float* __restrict__ yout) {
  __shared__ float bnd[(NW + 1) * BUFW];
  __shared__ int   flags[NW];
  __shared__ ull   bits[NW][11][65];   // win stride 65*8B = 2 mod 32 banks

  const int  tid  = threadIdx.x;
  const int  wave = tid >> 6;
  const int  lane = tid & 63;
  const int  img  = blockIdx.x;
  const bool l63  = (lane == 63);

  for (int i = tid; i < (NW + 1) * BUFW; i += 512) bnd[i] = 0.0f;
  if (tid < NW) flags[tid] = 0;
  bits[wave][10][lane] = 0ull;         // pad window (t64+1 == 10 reads)
  __syncthreads();

  const int r = wave * 64 + lane;
  const float* xrow = xin + (size_t)img * IMG + (size_t)r * WW;
  float* bufR = bnd + wave * BUFW;
  float* bufW = bnd + (wave + 1) * BUFW;
  const int c0 = -2 * lane;

  // (c & 511) keeps every access inside this lane's row; out-of-range columns
  // are poisoned to -8.0f at process time, so wrapped values are never used.
  auto ldx = [&](int c) -> float2 { return *(const float2*)(xrow + (c & 511)); };

  // Raw x pipeline: 4 slots x 4 float2 = columns [c0+8k, c0+8k+7] per slot.
  // iter8 K issues slot K%4 for K+4, and processes slot (K+1)%4 -> pq at its
  // bottom (that slot was issued 3 iter8s ago: arrived).
  float2 R0[4], R1[4], R2[4], R3[4];
#pragma unroll
  for (int i = 0; i < 4; ++i) {
    R0[i] = ldx(c0 + 0  + 2 * i);
    R1[i] = ldx(c0 + 8  + 2 * i);
    R2[i] = ldx(c0 + 16 + 2 * i);
    R3[i] = ldx(c0 + 24 + 2 * i);
  }

  float pq[8];                         // processed x for the CURRENT iter8
  auto proc = [&](float2 (&S)[4], int Tb) {
#pragma unroll
    for (int i = 0; i < 8; ++i) {
      float raw = (i & 1) ? S[i >> 1].y : S[i >> 1].x;
      int   c   = c0 + Tb + i;
      pq[i] = ((unsigned)c < 512u) ? pp(raw) : -8.0f;   // sentinel off-chain
    }
  };

  int seen = 0;                        // cached producer flag (monotonic)
  if (wave) {
    while ((seen = __hip_atomic_load(&flags[wave - 1], __ATOMIC_RELAXED,
                                     __HIP_MEMORY_SCOPE_WORKGROUP)) < LAG)
      __builtin_amdgcn_s_sleep(1);
    __asm__ volatile("s_waitcnt lgkmcnt(0)" ::: "memory");
  }

  proc(R0, 0);                         // pq = columns c0..c0+7 (iter8 K=0)

  float err = 0.0f, s2 = 0.0f;
  float s1 = (lane == 0) ? bufR[129] : 0.0f;
  // q pipeline: 2 slots, parity K%2; reloaded at iter8 bottom for K+2.
  float2 Q0[4], Q1[4];
#pragma unroll
  for (int i = 0; i < 4; ++i) {
    Q0[i] = *(const float2*)(bufR + 130 + 2 * i);   // for K=0 (steps 0..7)
    Q1[i] = *(const float2*)(bufR + 138 + 2 * i);   // for K=1 (steps 8..15)
  }

  unsigned accLo = 0u, accHi = 0u;

  auto step = [&](float qv, float xv) -> float {
#pragma clang fp contract(off)
    float e_in = wave_shr1(err, qv);          // err[r-1][c+1]
    float t1   = F_UL * s2;
    float t2   = F_U  * s1;
    float t3   = F_UR * e_in;
    float u    = (t1 + t2) + t3;              // ref's left-to-right order
    float a1   = xv + u;                      // xv = x01 (or -8 sentinel)
    float b    = F_L * err;
    float v    = a1 + b;
    float val  = __builtin_amdgcn_fmed3f(v, 0.0f, 1.0f);  // == clamp, 1 op
    float qn   = rintf(val);                  // round-half-even
    err = val - qn;                           // sentinel path: exactly 0
    s2 = s1; s1 = e_in;
    return qn;                                // 0.0f or 1.0f
  };

  auto iter8 = [&](float2 (&RL)[4], float2 (&RP)[4], float2 (&QC)[4],
                   int T, int bsh, unsigned& acc) {
    const int cg = c0 + T;
    // issue x loads for iter8 T+32 (consumed 4 iter8s later, slot renamed)
    RL[0] = ldx(cg + 32);
    RL[1] = ldx(cg + 34);
    RL[2] = ldx(cg + 36);
    RL[3] = ldx(cg + 38);

    float p0 = step(QC[0].x, pq[0]); float e0 = err;
    float p1 = step(QC[0].y, pq[1]); float e1 = err;
    float p2 = step(QC[1].x, pq[2]); float e2 = err;
    float p3 = step(QC[1].y, pq[3]); float e3 = err;
    float p4 = step(QC[2].x, pq[4]); float e4 = err;
    float p5 = step(QC[2].y, pq[5]); float e5 = err;
    float p6 = step(QC[3].x, pq[6]); float e6 = err;
    float p7 = step(QC[3].y, pq[7]); float e7 = err;

    // boundary prefetch for iteration T+16 (same slot, distance 2)
    QC[0] = *(const float2*)(bufR + (T + 146));
    QC[1] = *(const float2*)(bufR + (T + 148));
    QC[2] = *(const float2*)(bufR + (T + 150));
    QC[3] = *(const float2*)(bufR + (T + 152));

    // process raw slot for the NEXT iter8 (columns T+8; loaded 3 iter8s ago)
    proc(RP, T + 8);

    // bit = exponent bit 29 of qn (1.0f -> 1, 0.0f -> 0); off-chain
    acc |= ((__float_as_uint(p0) >> 29) & 1u) << (bsh + 0);
    acc |= ((__float_as_uint(p1) >> 29) & 1u) << (bsh + 1);
    acc |= ((__float_as_uint(p2) >> 29) & 1u) << (bsh + 2);
    acc |= ((__float_as_uint(p3) >> 29) & 1u) << (bsh + 3);
    acc |= ((__float_as_uint(p4) >> 29) & 1u) << (bsh + 4);
    acc |= ((__float_as_uint(p5) >> 29) & 1u) << (bsh + 5);
    acc |= ((__float_as_uint(p6) >> 29) & 1u) << (bsh + 6);
    acc |= ((__float_as_uint(p7) >> 29) & 1u) << (bsh + 7);

    if (l63) {  // boundary row for next wave; base = T-126+129 = T+3
      float* bw = bufW + (T + 3);
      bw[0] = e0; bw[1] = e1; bw[2] = e2; bw[3] = e3;
      bw[4] = e4; bw[5] = e5; bw[6] = e6; bw[7] = e7;
    }
  };

  auto waitflag = [&](int j) {
    if (wave) {
      int need = j + LAG; if (need > NCH) need = NCH;
      if (seen < need) {
        while ((seen = __hip_atomic_load(&flags[wave - 1], __ATOMIC_RELAXED,
                                         __HIP_MEMORY_SCOPE_WORKGROUP)) < need)
          __builtin_amdgcn_s_sleep(1);
        __asm__ volatile("s_waitcnt lgkmcnt(0)" ::: "memory");
      }
    }
  };
  auto pubflag = [&](int v) {
    if (l63) {
      __asm__ volatile("s_waitcnt lgkmcnt(0)" ::: "memory");
      __hip_atomic_store(&flags[wave], v, __ATOMIC_RELAXED,
                         __HIP_MEMORY_SCOPE_WORKGROUP);
    }
  };

  // body = 4 chunks = 8 iter8s = one 64-step bit window
  for (int jj = 0; jj < NCH; jj += 4) {
    const int T0 = 16 * jj;
    waitflag(jj);
    iter8(R0, R1, Q0, T0 + 0,  0,  accLo);
    iter8(R1, R2, Q1, T0 + 8,  8,  accLo);
    pubflag(jj + 1);
    waitflag(jj + 1);
    iter8(R2, R3, Q0, T0 + 16, 16, accLo);
    iter8(R3, R0, Q1, T0 + 24, 24, accLo);
    pubflag(jj + 2);
    waitflag(jj + 2);
    iter8(R0, R1, Q0, T0 + 32, 0,  accHi);
    iter8(R1, R2, Q1, T0 + 40, 8,  accHi);
    pubflag(jj + 3);
    waitflag(jj + 3);
    iter8(R2, R3, Q0, T0 + 48, 16, accHi);
    iter8(R3, R0, Q1, T0 + 56, 24, accHi);
    pubflag(jj + 4);
    *(uint2*)&bits[wave][jj >> 2][lane] = make_uint2(accLo, accHi);
    accLo = 0u; accHi = 0u;
  }

  // ---- unpack tail: this wave's 64 rows, bits (LDS) -> ±1.0f coalesced ----
  float* ybase = yout + (size_t)img * IMG + (size_t)(wave * 64) * WW + 8 * lane;
  for (int rr = 0; rr < 64; ++rr) {
    const int t0 = 8 * lane + 2 * rr;         // first bit index
    const int t64 = t0 >> 6, sh = t0 & 63;    // sh even, <= 62
    ull w1 = bits[wave][t64][rr];
    ull w2 = bits[wave][t64 + 1][rr];         // pad window covers t64==9
    unsigned b = (unsigned)((w1 >> sh) | ((w2 << 1) << (63 - sh)));
    float* orow = ybase + (size_t)rr * WW;
    float4 v0, v1;
    v0.x = (b & 1u)   ? 1.0f : -1.0f;
    v0.y = (b & 2u)   ? 1.0f : -1.0f;
    v0.z = (b & 4u)   ? 1.0f : -1.0f;
    v0.w = (b & 8u)   ? 1.0f : -1.0f;
    v1.x = (b & 16u)  ? 1.0f : -1.0f;
    v1.y = (b & 32u)  ? 1.0f : -1.0f;
    v1.z = (b & 64u)  ? 1.0f : -1.0f;
    v1.w = (b & 128u) ? 1.0f : -1.0f;
    *(float4*)(orow)     = v0;
    *(float4*)(orow + 4) = v1;
  }
}

extern "C" void kernel_launch(void* const* d_in, const int* in_sizes, int n_in,
                              void* d_out, int out_size, void* d_ws, size_t ws_size,
                              hipStream_t stream) {
  const float* x = (const float*)d_in[0];
  float*       y = (float*)d_out;
  dither_fused<<<dim3(NIMG), dim3(512), 0, stream>>>(x, y);
}

// Round 4
// 282.664 us; speedup vs baseline: 1.7873x; 1.1112x over previous
//
#include <hip/hip_runtime.h>

// Floyd-Steinberg dithering, BIT_WIDTH=1. 96 images of 512x512 fp32.
// Round 11: back to the proven R1 structure (xp skew in global), two changes:
//  1) dither: 4 waves x 2 passes instead of 8 waves. Same wavefront schedule
//     (pass p = band p, staggered LAG chunks; flags/boundaries indexed by
//     pass), but only 1 wave/SIMD -> the ~2x SIMD issue contention measured
//     in R1 (106 cyc/step vs ~45 cyc chain) is gone. Schedule is exactly
//     balanced: pass p starts at p*160 steps, wave w frees at (w+4)*160.
//  2) unpack fused as a tail: bits -> LDS (padded, conflict-free), each wave
//     writes its two bands (128 rows) as coalesced float4s. Third kernel and
//     yb round-trip eliminated.
// R3 lesson: per-lane direct x loads = 64 lines/instr, MSHR-bound; the
// global xp skew materialization is the correct staging for the 128-col
// diagonal span (too big for LDS).
// Bit-exactness (R1-R10, absmax 0.0): ref op order, rintf (round-half-even),
// contract OFF, med3(v,0,1)==min(max(v,0),1) for non-NaN, -8 sentinel makes
// out-of-range err==0 exactly.

#define F_UL 0.0625f   // 1/16
#define F_U  0.3125f   // 5/16
#define F_UR 0.1875f   // 3/16
#define F_L  0.4375f   // 7/16

typedef unsigned long long ull;

constexpr int WW    = 512;
constexpr int IMG   = WW * WW;
constexpr int NIMG  = 96;
constexpr int NW    = 8;      // bands per image (= passes)
constexpr int BUFW  = 792;    // boundary region floats (+128 base offset)
constexpr int NCH   = 40;     // 16-step chunks (640 steps per pass)
constexpr int LAG   = 10;     // producer lead in chunks
constexpr int PPAIR = 320;    // step-pairs per (img,band) region
constexpr size_t XP_FLOATS = (size_t)NIMG * NW * PPAIR * 128;
constexpr size_t XP_BYTES  = XP_FLOATS * 4;        // 125,829,120 B
constexpr size_t XP_SLACK  = 8192;                 // prefetch overrun (16 pairs)
constexpr size_t XP_OFF    = 4u * 1024 * 1024;
constexpr size_t WS_NEED   = XP_OFF + XP_BYTES + XP_SLACK;

__device__ __forceinline__ float wave_shr1(float v, float fill) {
  int r = __builtin_amdgcn_update_dpp(__float_as_int(fill), __float_as_int(v),
                                      0x138 /*wave_shr:1*/, 0xF, 0xF, false);
  return __int_as_float(r);
}

__device__ __forceinline__ float pp(float xv) {   // x -> x01, ref op order
#pragma clang fp contract(off)
  float xc = fminf(fmaxf(xv, -1.0f), 1.0f);
  return (xc + 1.0f) * 0.5f;
}

// ---------------- pack: x -> skewed, preprocessed xp (proven R8/R1) --------
__global__ __launch_bounds__(256)
void pack_kernel(const float* __restrict__ xin, float* __restrict__ xp) {
  __shared__ float ring[4 * 4160];     // 4 slots x 64*65 floats
  const int img = blockIdx.x, w = blockIdx.y;
  const int tid = threadIdx.x;
  const int wv  = tid >> 6, l = tid & 63;

  const float* xg = xin + (size_t)img * IMG + (size_t)w * 64 * WW;
  float* ob = xp + ((size_t)(img * NW + w) * PPAIR) * 128;

  auto load_tile = [&](int t) {        // tile t = cols 64t..64t+63 -> slot t&3
    float* dst = ring + (t & 3) * 4160;
    const float* src = xg + 64 * t;
#pragma unroll
    for (int k = 0; k < 4; ++k) {
      int flat = tid + 256 * k;
      int row = flat >> 4, cq = flat & 15;
      float4 v = *(const float4*)(src + row * WW + cq * 4);
      float* d = dst + row * 65 + cq * 4;
      d[0] = pp(v.x); d[1] = pp(v.y); d[2] = pp(v.z); d[3] = pp(v.w);
    }
  };

  load_tile(0);
  __syncthreads();
  for (int t = 0; t < 10; ++t) {
    if (t < 7) load_tile(t + 1);
    const int Mb = 32 * t + 8 * wv;
#pragma unroll
    for (int i = 0; i < 8; ++i) {
      const int M  = Mb + i;
      const int g  = 2 * (M - l);            // global column of first element
      const int gm = g & 511;                // safe LDS index for invalid g
      const int idx = ((gm >> 6) & 3) * 4160 + l * 65 + (gm & 63);
      const bool ok = ((unsigned)g < 512u);
      float va = ring[idx], vb = ring[idx + 1];
      float2 v = make_float2(ok ? va : -8.0f, ok ? vb : -8.0f);
      *(float2*)(ob + (size_t)M * 128 + 2 * l) = v;   // 512B coalesced / wave
    }
    __syncthreads();
  }
}

// ------------- dither: 4 waves x 2 passes, fused unpack tail ---------------
__global__ __launch_bounds__(256, 1)
void dither_packed4(const float* __restrict__ xp, float* __restrict__ yout) {
  __shared__ float bnd[(NW + 1) * BUFW];
  __shared__ int   flags[NW];
  __shared__ ull   bits[NW][11][65];   // [pass][window(+pad)][row(+pad)]

  const int  tid  = threadIdx.x;       // 0..255
  const int  wave = tid >> 6;          // 0..3
  const int  lane = tid & 63;
  const int  img  = blockIdx.x;
  const bool l63  = (lane == 63);

  for (int i = tid; i < (NW + 1) * BUFW; i += 256) bnd[i] = 0.0f;
  if (tid < NW) flags[tid] = 0;
  bits[wave][10][lane] = 0ull;         // pad windows (t64+1 == 10 reads)
  bits[wave + 4][10][lane] = 0ull;
  __syncthreads();

  for (int half = 0; half < 2; ++half) {
    const int p = wave + 4 * half;     // pass = band index 0..7
    const float* xw = xp + ((size_t)(img * NW + p) * PPAIR) * 128 + lane * 2;
    float* bufR = bnd + p * BUFW;
    float* bufW = bnd + (p + 1) * BUFW;
    ull*   bitp = &bits[p][0][0];      // window stride 65 ulls

    // x pipeline: 8 slots x 4 float2. iter8 K consumes slot K%8, loads slot
    // (K+4)%8 with pairs for iter8 K+4 -> loads live 4 iter8s, zero copies.
    float2 X0[4], X1[4], X2[4], X3[4], X4[4], X5[4], X6[4], X7[4];
#pragma unroll
    for (int i = 0; i < 4; ++i) {
      X0[i] = *(const float2*)(xw + (size_t)(0  + i) * 128);
      X1[i] = *(const float2*)(xw + (size_t)(4  + i) * 128);
      X2[i] = *(const float2*)(xw + (size_t)(8  + i) * 128);
      X3[i] = *(const float2*)(xw + (size_t)(12 + i) * 128);
    }

    int seen = 0;                      // cached producer flag (monotonic)
    if (p) {
      while ((seen = __hip_atomic_load(&flags[p - 1], __ATOMIC_RELAXED,
                                       __HIP_MEMORY_SCOPE_WORKGROUP)) < LAG)
        __builtin_amdgcn_s_sleep(1);
      __asm__ volatile("s_waitcnt lgkmcnt(0)" ::: "memory");
    }

    float err = 0.0f, s2 = 0.0f;
    float s1 = (lane == 0) ? bufR[129] : 0.0f;
    // q pipeline: 2 slots, parity K%2; reloaded at iter8 bottom for K+2.
    float2 Q0[4], Q1[4];
#pragma unroll
    for (int i = 0; i < 4; ++i) {
      Q0[i] = *(const float2*)(bufR + 130 + 2 * i);   // for K=0 (steps 0..7)
      Q1[i] = *(const float2*)(bufR + 138 + 2 * i);   // for K=1 (steps 8..15)
    }

    unsigned accLo = 0u, accHi = 0u;

    auto step = [&](float qv, float xv) -> float {
#pragma clang fp contract(off)
      float e_in = wave_shr1(err, qv);          // err[r-1][c+1]
      float t1   = F_UL * s2;
      float t2   = F_U  * s1;
      float t3   = F_UR * e_in;
      float u    = (t1 + t2) + t3;              // ref's left-to-right order
      float a1   = xv + u;                      // xv = x01 (or -8 sentinel)
      float b    = F_L * err;
      float v    = a1 + b;
      float val  = __builtin_amdgcn_fmed3f(v, 0.0f, 1.0f);  // == clamp
      float qn   = rintf(val);                  // round-half-even
      err = val - qn;                           // sentinel path: exactly 0
      s2 = s1; s1 = e_in;
      return qn;                                // 0.0f or 1.0f
    };

    auto iter8 = [&](float2 (&XC)[4], float2 (&XL)[4], float2 (&QC)[4],
                     int T, int bsh, unsigned& acc) {
      // x prefetch: pairs T/2+16..19 (consumed 4 iter8s later, slot renamed)
      const float* lp = xw + (size_t)(T / 2 + 16) * 128;
      XL[0] = *(const float2*)(lp + 0 * 128);
      XL[1] = *(const float2*)(lp + 1 * 128);
      XL[2] = *(const float2*)(lp + 2 * 128);
      XL[3] = *(const float2*)(lp + 3 * 128);

      float p0 = step(QC[0].x, XC[0].x); float e0 = err;
      float p1 = step(QC[0].y, XC[0].y); float e1 = err;
      float p2 = step(QC[1].x, XC[1].x); float e2 = err;
      float p3 = step(QC[1].y, XC[1].y); float e3 = err;
      float p4 = step(QC[2].x, XC[2].x); float e4 = err;
      float p5 = step(QC[2].y, XC[2].y); float e5 = err;
      float p6 = step(QC[3].x, XC[3].x); float e6 = err;
      float p7 = step(QC[3].y, XC[3].y); float e7 = err;

      // boundary prefetch for iteration T+16 (same slot, distance 2)
      QC[0] = *(const float2*)(bufR + (T + 146));
      QC[1] = *(const float2*)(bufR + (T + 148));
      QC[2] = *(const float2*)(bufR + (T + 150));
      QC[3] = *(const float2*)(bufR + (T + 152));

      // bit = exponent bit 29 of qn (1.0f -> 1, 0.0f -> 0); off-chain
      acc |= ((__float_as_uint(p0) >> 29) & 1u) << (bsh + 0);
      acc |= ((__float_as_uint(p1) >> 29) & 1u) << (bsh + 1);
      acc |= ((__float_as_uint(p2) >> 29) & 1u) << (bsh + 2);
      acc |= ((__float_as_uint(p3) >> 29) & 1u) << (bsh + 3);
      acc |= ((__float_as_uint(p4) >> 29) & 1u) << (bsh + 4);
      acc |= ((__float_as_uint(p5) >> 29) & 1u) << (bsh + 5);
      acc |= ((__float_as_uint(p6) >> 29) & 1u) << (bsh + 6);
      acc |= ((__float_as_uint(p7) >> 29) & 1u) << (bsh + 7);

      if (l63) {  // boundary row for next pass; base = T-126+129 = T+3
        float* bw = bufW + (T + 3);
        bw[0] = e0; bw[1] = e1; bw[2] = e2; bw[3] = e3;
        bw[4] = e4; bw[5] = e5; bw[6] = e6; bw[7] = e7;
      }
    };

    auto waitflag = [&](int j) {
      if (p) {
        int need = j + LAG; if (need > NCH) need = NCH;
        if (seen < need) {
          while ((seen = __hip_atomic_load(&flags[p - 1], __ATOMIC_RELAXED,
                                           __HIP_MEMORY_SCOPE_WORKGROUP)) < need)
            __builtin_amdgcn_s_sleep(1);
          __asm__ volatile("s_waitcnt lgkmcnt(0)" ::: "memory");
        }
      }
    };
    auto pubflag = [&](int v) {
      if (l63) {
        __asm__ volatile("s_waitcnt lgkmcnt(0)" ::: "memory");
        __hip_atomic_store(&flags[p], v, __ATOMIC_RELAXED,
                           __HIP_MEMORY_SCOPE_WORKGROUP);
      }
    };

    // body = 4 chunks = 8 iter8s = one 64-step bit window
    for (int jj = 0; jj < NCH; jj += 4) {
      const int T0 = 16 * jj;
      waitflag(jj);
      iter8(X0, X4, Q0, T0 + 0,  0,  accLo);
      iter8(X1, X5, Q1, T0 + 8,  8,  accLo);
      pubflag(jj + 1);
      waitflag(jj + 1);
      iter8(X2, X6, Q0, T0 + 16, 16, accLo);
      iter8(X3, X7, Q1, T0 + 24, 24, accLo);
      pubflag(jj + 2);
      waitflag(jj + 2);
      iter8(X4, X0, Q0, T0 + 32, 0,  accHi);
      iter8(X5, X1, Q1, T0 + 40, 8,  accHi);
      pubflag(jj + 3);
      waitflag(jj + 3);
      iter8(X6, X2, Q0, T0 + 48, 16, accHi);
      iter8(X7, X3, Q1, T0 + 56, 24, accHi);
      pubflag(jj + 4);
      *(uint2*)(bitp + (size_t)(jj >> 2) * 65 + lane) = make_uint2(accLo, accHi);
      accLo = 0u; accHi = 0u;
    }
  }

  // ---- unpack tail: this wave's two bands, bits (LDS) -> ±1.0f coalesced --
  for (int half = 0; half < 2; ++half) {
    const int p = wave + 4 * half;
    float* ybase = yout + (size_t)img * IMG + (size_t)(p * 64) * WW + 8 * lane;
    for (int rr = 0; rr < 64; ++rr) {
      const int t0 = 8 * lane + 2 * rr;         // first bit index
      const int t64 = t0 >> 6, sh = t0 & 63;    // sh even, <= 62
      ull w1 = bits[p][t64][rr];
      ull w2 = bits[p][t64 + 1][rr];            // pad window covers t64==9
      unsigned b = (unsigned)((w1 >> sh) | ((w2 << 1) << (63 - sh)));
      float* orow = ybase + (size_t)rr * WW;
      float4 v0, v1;
      v0.x = (b & 1u)   ? 1.0f : -1.0f;
      v0.y = (b & 2u)   ? 1.0f : -1.0f;
      v0.z = (b & 4u)   ? 1.0f : -1.0f;
      v0.w = (b & 8u)   ? 1.0f : -1.0f;
      v1.x = (b & 16u)  ? 1.0f : -1.0f;
      v1.y = (b & 32u)  ? 1.0f : -1.0f;
      v1.z = (b & 64u)  ? 1.0f : -1.0f;
      v1.w = (b & 128u) ? 1.0f : -1.0f;
      *(float4*)(orow)     = v0;
      *(float4*)(orow + 4) = v1;
    }
  }
}

// ---------------- fallback: R4/R6 direct-x kernel (known-good) --------------
__global__ __launch_bounds__(512, 1)
void dither_direct(const float* __restrict__ xin, float* __restrict__ yout) {
  __shared__ float bnd[(NW + 1) * BUFW];
  __shared__ int flags[NW];

  const int  tid  = threadIdx.x;
  const int  wave = tid >> 6;
  const int  lane = tid & 63;
  const int  img  = blockIdx.x;
  const bool l63  = (lane == 63);

  for (int i = tid; i < (NW + 1) * BUFW; i += 512) bnd[i] = 0.0f;
  if (tid < NW) flags[tid] = 0;
  __syncthreads();

  const int r = wave * 64 + lane;
  const float* xrow = xin + (size_t)img * IMG + (size_t)r * WW;
  float*       yrow = yout + (size_t)img * IMG + (size_t)r * WW;
  float* bufR = bnd + wave * BUFW;
  float* bufW = bnd + (wave + 1) * BUFW;
  const int c0 = -2 * lane;

  auto ldx = [&](int c) -> float2 { return *(const float2*)(xrow + (c & 511)); };

  float2 A0 = ldx(c0 + 0),  A1 = ldx(c0 + 2),  A2 = ldx(c0 + 4),  A3 = ldx(c0 + 6);
  float2 pB0 = ldx(c0 + 8),  pB1 = ldx(c0 + 10), pB2 = ldx(c0 + 12), pB3 = ldx(c0 + 14);
  float2 pC0 = ldx(c0 + 16), pC1 = ldx(c0 + 18), pC2 = ldx(c0 + 20), pC3 = ldx(c0 + 22);
  float xq0 = pp(A0.x), xq1 = pp(A0.y), xq2 = pp(A1.x), xq3 = pp(A1.y);
  float xq4 = pp(A2.x), xq5 = pp(A2.y), xq6 = pp(A3.x), xq7 = pp(A3.y);
  float2 pA0 = pB0, pA1 = pB1, pA2 = pB2, pA3 = pB3;
  pB0 = pC0; pB1 = pC1; pB2 = pC2; pB3 = pC3;

  if (wave) {
    while (__hip_atomic_load(&flags[wave - 1], __ATOMIC_RELAXED,
                             __HIP_MEMORY_SCOPE_WORKGROUP) < LAG)
      __builtin_amdgcn_s_sleep(1);
    __asm__ volatile("s_waitcnt lgkmcnt(0)" ::: "memory");
  }

  float err = 0.0f, s2 = 0.0f;
  float s1 = (lane == 0) ? bufR[129] : 0.0f;
  float2 qa = *(const float2*)(bufR + 130);
  float2 qb = *(const float2*)(bufR + 132);
  float2 qc = *(const float2*)(bufR + 134);
  float2 qd = *(const float2*)(bufR + 136);
  float2 fa = *(const float2*)(bufR + 138);
  float2 fb = *(const float2*)(bufR + 140);
  float2 fc = *(const float2*)(bufR + 142);
  float2 fd = *(const float2*)(bufR + 144);

  auto step = [&](int c, float qv, float xv) -> float {
#pragma clang fp contract(off)
    float e_in = wave_shr1(err, qv);
    float t1   = F_UL * s2;
    float t2   = F_U  * s1;
    float t3   = F_UR * e_in;
    float u    = (t1 + t2) + t3;
    float a1   = xv + u;
    float b    = F_L * err;
    float v    = a1 + b;
    float val  = fminf(fmaxf(v, 0.0f), 1.0f);
    float qn   = rintf(val);
    float e    = val - qn;
    float en   = ((unsigned)c < 512u) ? e : 0.0f;
    err = en; s2 = s1; s1 = e_in;
    return __builtin_fmaf(qn, 2.0f, -1.0f);
  };

  auto iter8 = [&](int T) {
    const int cg = c0 + T;
    float2 n0 = ldx(cg + 24), n1 = ldx(cg + 26), n2 = ldx(cg + 28), n3 = ldx(cg + 30);
    float2 h0 = *(const float2*)(bufR + (T + 146));
    float2 h1 = *(const float2*)(bufR + (T + 148));
    float2 h2 = *(const float2*)(bufR + (T + 150));
    float2 h3 = *(const float2*)(bufR + (T + 152));
    float w0 = pp(pA0.x), w1 = pp(pA0.y), w2 = pp(pA1.x), w3 = pp(pA1.y);
    float w4 = pp(pA2.x), w5 = pp(pA2.y), w6 = pp(pA3.x), w7 = pp(pA3.y);

    float y0 = step(cg + 0, qa.x, xq0); float e0 = err;
    float y1 = step(cg + 1, qa.y, xq1); float e1 = err;
    float y2 = step(cg + 2, qb.x, xq2); float e2 = err;
    float y3 = step(cg + 3, qb.y, xq3); float e3 = err;
    float y4 = step(cg + 4, qc.x, xq4); float e4 = err;
    float y5 = step(cg + 5, qc.y, xq5); float e5 = err;
    float y6 = step(cg + 6, qd.x, xq6); float e6 = err;
    float y7 = step(cg + 7, qd.y, xq7); float e7 = err;

    if ((unsigned)(cg + 0) < 511u) *(float2*)(yrow + cg + 0) = make_float2(y0, y1);
    if ((unsigned)(cg + 2) < 511u) *(float2*)(yrow + cg + 2) = make_float2(y2, y3);
    if ((unsigned)(cg + 4) < 511u) *(float2*)(yrow + cg + 4) = make_float2(y4, y5);
    if ((unsigned)(cg + 6) < 511u) *(float2*)(yrow + cg + 6) = make_float2(y6, y7);

    if (l63) {
      float* bw = bufW + (cg + 129);
      bw[0] = e0; bw[1] = e1; bw[2] = e2; bw[3] = e3;
      bw[4] = e4; bw[5] = e5; bw[6] = e6; bw[7] = e7;
    }

    xq0 = w0; xq1 = w1; xq2 = w2; xq3 = w3;
    xq4 = w4; xq5 = w5; xq6 = w6; xq7 = w7;
    pA0 = pB0; pA1 = pB1; pA2 = pB2; pA3 = pB3;
    pB0 = n0;  pB1 = n1;  pB2 = n2;  pB3 = n3;
    qa = fa; qb = fb; qc = fc; qd = fd;
    fa = h0; fb = h1; fc = h2; fd = h3;
  };

  for (int j = 0; j < NCH; ++j) {
    if (wave) {
      int need = j + LAG; if (need > NCH) need = NCH;
      while (__hip_atomic_load(&flags[wave - 1], __ATOMIC_RELAXED,
                               __HIP_MEMORY_SCOPE_WORKGROUP) < need)
        __builtin_amdgcn_s_sleep(1);
      __asm__ volatile("s_waitcnt lgkmcnt(0)" ::: "memory");
    }
    iter8(16 * j);
    iter8(16 * j + 8);
    if (l63) {
      __asm__ volatile("s_waitcnt lgkmcnt(0)" ::: "memory");
      __hip_atomic_store(&flags[wave], j + 1, __ATOMIC_RELAXED,
                         __HIP_MEMORY_SCOPE_WORKGROUP);
    }
  }
}

extern "C" void kernel_launch(void* const* d_in, const int* in_sizes, int n_in,
                              void* d_out, int out_size, void* d_ws, size_t ws_size,
                              hipStream_t stream) {
  const float* x = (const float*)d_in[0];
  float*       y = (float*)d_out;
  if (ws_size >= WS_NEED) {
    float* xp = (float*)((char*)d_ws + XP_OFF);
    pack_kernel<<<dim3(NIMG, NW), dim3(256), 0, stream>>>(x, xp);
    dither_packed4<<<dim3(NIMG), dim3(256), 0, stream>>>(xp, y);
  } else {
    dither_direct<<<dim3(NIMG), dim3(512), 0, stream>>>(x, y);
  }
}